// Round 3
// baseline (243.944 us; speedup 1.0000x reference)
//
#include <hip/hip_runtime.h>
#include <hip/hip_bf16.h>

#define OUT_DIM 256
#define COND_DIM 512
#define NODE_DIM 256
#define TM 64
#define LDA 264          // bf16 A-tile row stride (+8 pad)
#define SCAN_T 1024
#define LN_EPS 1e-5f

typedef __attribute__((ext_vector_type(8))) short bf16x8;
typedef __attribute__((ext_vector_type(4))) float f32x4;

__device__ inline unsigned short f2bf(float f) {
    unsigned u = __float_as_uint(f);
    u += 0x7fffu + ((u >> 16) & 1u);           // RNE
    return (unsigned short)(u >> 16);
}
__device__ inline float bf2f(unsigned short b) {
    return __uint_as_float((unsigned)b << 16);
}

// ---------------- fused: zero counts/cursor + Wl->bf16 transpose + FiLM params
// grid = 48 blocks: [0,16) convb tiles, [16,48) film columns
__global__ __launch_bounds__(256) void prep_kernel(
        const float* __restrict__ Wl, unsigned short* __restrict__ WlT,
        const float* __restrict__ cond, const float* __restrict__ Wc,
        const float* __restrict__ bc, float* __restrict__ gamma, float* __restrict__ beta,
        int* __restrict__ zero_base, int zero_n) {
    __shared__ float lds[64 * 65];
    // grid-stride zero of counts+cursor (2N ints)
    for (int i = blockIdx.x * 256 + threadIdx.x; i < zero_n; i += gridDim.x * 256)
        zero_base[i] = 0;

    if (blockIdx.x < 16) {
        // transpose+convert Wl [256x256] row-major -> WlT[n*256+k] bf16
        float (*tile)[65] = (float(*)[65])lds;
        int bx = blockIdx.x & 3, by = blockIdx.x >> 2;
        int tr = threadIdx.x >> 6, tc = threadIdx.x & 63;
        #pragma unroll
        for (int rr = 0; rr < 64; rr += 4)
            tile[rr + tr][tc] = Wl[(by * 64 + rr + tr) * OUT_DIM + bx * 64 + tc];
        __syncthreads();
        #pragma unroll
        for (int rr = 0; rr < 64; rr += 4) {
            int n = bx * 64 + rr + tr;
            int k = by * 64 + tc;
            WlT[n * NODE_DIM + k] = f2bf(tile[tc][rr + tr]);
        }
    } else {
        int bf = blockIdx.x - 16;
        int b = bf >> 1, half = bf & 1;
        int o = half * 256 + threadIdx.x;
        float* c = lds;
        for (int k = threadIdx.x; k < COND_DIM; k += 256) c[k] = cond[b * COND_DIM + k];
        __syncthreads();
        float acc = bc[o];
        for (int k = 0; k < COND_DIM; k += 4) {
            float4 cv = *(const float4*)&c[k];
            acc += cv.x * Wc[(k + 0) * 512 + o];
            acc += cv.y * Wc[(k + 1) * 512 + o];
            acc += cv.z * Wc[(k + 2) * 512 + o];
            acc += cv.w * Wc[(k + 3) * 512 + o];
        }
        if (half == 0) gamma[b * 256 + threadIdx.x] = acc + 1.0f;
        else           beta[b * 256 + threadIdx.x] = acc;
    }
}

// ---------------- x(bf16) = relu(LN(nf @ Wl) * gamma[bid] + beta[bid]) via MFMA
// also fused: degree count atomics (independent of the GEMM work)
__global__ __launch_bounds__(256) void node_mfma_kernel(
        const float* __restrict__ nf, const unsigned short* __restrict__ WlT,
        const int* __restrict__ batch_ids, const float* __restrict__ gamma,
        const float* __restrict__ beta, unsigned short* __restrict__ xout, int N,
        const int* __restrict__ ni, int* __restrict__ counts, int E) {
    __shared__ unsigned short Atile[TM * LDA];
    __shared__ int bid_s[TM];
    int t = threadIdx.x;
    int n0 = blockIdx.x * TM;

    // fused degree count (fire-and-forget global atomics)
    for (int e = blockIdx.x * 256 + t; e < E; e += gridDim.x * 256)
        atomicAdd(&counts[ni[e]], 1);

    // stage A: 64 rows x 256 fp32 -> bf16 LDS
    #pragma unroll
    for (int it = 0; it < 16; ++it) {
        int idx = t + it * 256;
        int r = idx >> 6;
        int c4 = idx & 63;
        int row = n0 + r;
        float4 v;
        if (row < N) v = *(const float4*)&nf[(size_t)row * NODE_DIM + c4 * 4];
        else         v = make_float4(0.f, 0.f, 0.f, 0.f);
        unsigned* dst = (unsigned*)&Atile[r * LDA + c4 * 4];
        dst[0] = (unsigned)f2bf(v.x) | ((unsigned)f2bf(v.y) << 16);
        dst[1] = (unsigned)f2bf(v.z) | ((unsigned)f2bf(v.w) << 16);
    }
    if (t < TM) bid_s[t] = (n0 + t < N) ? batch_ids[n0 + t] : 0;
    __syncthreads();

    int wave = t >> 6;
    int lane = t & 63;
    int l = lane & 15;
    int quad = lane >> 4;

    f32x4 acc[16];
    #pragma unroll
    for (int ct = 0; ct < 16; ++ct) acc[ct] = (f32x4){0.f, 0.f, 0.f, 0.f};

    const unsigned short* Abase = &Atile[(wave * 16 + l) * LDA + quad * 8];
    const unsigned short* Bbase = &WlT[l * NODE_DIM + quad * 8];

    #pragma unroll
    for (int ks = 0; ks < 8; ++ks) {
        bf16x8 a = *(const bf16x8*)(Abase + ks * 32);
        #pragma unroll
        for (int ct = 0; ct < 16; ++ct) {
            bf16x8 b = *(const bf16x8*)(Bbase + ct * 16 * NODE_DIM + ks * 32);
            acc[ct] = __builtin_amdgcn_mfma_f32_16x16x32_bf16(a, b, acc[ct], 0, 0, 0);
        }
    }

    // epilogue: LN + FiLM + relu + bf16 store
    #pragma unroll
    for (int reg = 0; reg < 4; ++reg) {
        float s = 0.f, s2 = 0.f;
        #pragma unroll
        for (int ct = 0; ct < 16; ++ct) {
            float v = acc[ct][reg];
            s += v; s2 += v * v;
        }
        #pragma unroll
        for (int off = 1; off <= 8; off <<= 1) {
            s += __shfl_xor(s, off);
            s2 += __shfl_xor(s2, off);
        }
        float mu = s * (1.f / OUT_DIM);
        float var = s2 * (1.f / OUT_DIM) - mu * mu;
        float rs = rsqrtf(var + LN_EPS);
        int lrow = wave * 16 + quad * 4 + reg;
        int grow = n0 + lrow;
        int bid = bid_s[lrow];
        const float* gg = &gamma[bid * OUT_DIM];
        const float* gb = &beta[bid * OUT_DIM];
        if (grow < N) {
            unsigned short* orow = &xout[(size_t)grow * OUT_DIM];
            #pragma unroll
            for (int ct = 0; ct < 16; ++ct) {
                int col = ct * 16 + l;
                float v = (acc[ct][reg] - mu) * rs;
                v = v * gg[col] + gb[col];
                orow[col] = f2bf(fmaxf(v, 0.f));
            }
        }
    }
}

// ---------------- single-block exclusive scan of counts -> row_start[0..N]
__global__ __launch_bounds__(SCAN_T) void scan_kernel(const int* __restrict__ counts,
                                                      int* __restrict__ row_start, int N) {
    __shared__ int ssum[SCAN_T];
    int t = threadIdx.x;
    int per = (N + SCAN_T - 1) / SCAN_T;
    int base = t * per;
    int sum = 0;
    for (int i = 0; i < per; ++i) {
        int idx = base + i;
        if (idx < N) sum += counts[idx];
    }
    ssum[t] = sum;
    __syncthreads();
    for (int off = 1; off < SCAN_T; off <<= 1) {
        int v = (t >= off) ? ssum[t - off] : 0;
        __syncthreads();
        ssum[t] += v;
        __syncthreads();
    }
    int run = ssum[t] - sum;
    for (int i = 0; i < per; ++i) {
        int idx = base + i;
        if (idx < N) { row_start[idx] = run; run += counts[idx]; }
    }
    if (t == SCAN_T - 1) row_start[N] = ssum[SCAN_T - 1];
}

// ---------------- CSR fill (packed src idx + weight)
__global__ void fill_kernel(const int* __restrict__ nj, const int* __restrict__ ni,
                            const float* __restrict__ ew, const float* __restrict__ ep,
                            const int* __restrict__ row_start, int* __restrict__ cursor,
                            int2* __restrict__ epk, int E) {
    int e = blockIdx.x * blockDim.x + threadIdx.x;
    if (e < E) {
        int i = ni[e];
        int pos = row_start[i] + atomicAdd(&cursor[i], 1);
        epk[pos] = make_int2(nj[e], __float_as_int(ew[e] * ep[e]));
    }
}

// ---------------- aggregation: one wave per destination node, bf16 gather
__global__ void agg_kernel(const unsigned short* __restrict__ x, const int2* __restrict__ epk,
                           const int* __restrict__ row_start, float* __restrict__ out, int N) {
    int node = blockIdx.x * 4 + (threadIdx.x >> 6);
    int lane = threadIdx.x & 63;
    if (node >= N) return;
    int s = row_start[node], e = row_start[node + 1];
    float a0 = 0.f, a1 = 0.f, a2 = 0.f, a3 = 0.f;
    for (int p = s; p < e; ++p) {
        int2 pk = epk[p];
        int j = pk.x;
        float w = __int_as_float(pk.y);
        ushort4 xv = *(const ushort4*)&x[(size_t)j * OUT_DIM + lane * 4];
        a0 += bf2f(xv.x) * w;
        a1 += bf2f(xv.y) * w;
        a2 += bf2f(xv.z) * w;
        a3 += bf2f(xv.w) * w;
    }
    float4 o;
    o.x = fmaxf(a0, 0.f); o.y = fmaxf(a1, 0.f);
    o.z = fmaxf(a2, 0.f); o.w = fmaxf(a3, 0.f);
    *(float4*)&out[(size_t)node * OUT_DIM + lane * 4] = o;
}

extern "C" void kernel_launch(void* const* d_in, const int* in_sizes, int n_in,
                              void* d_out, int out_size, void* d_ws, size_t ws_size,
                              hipStream_t stream) {
    const float* node_feats = (const float*)d_in[0];
    const float* cond_feats = (const float*)d_in[1];
    const int*   batch_ids  = (const int*)d_in[2];
    const int*   node_j     = (const int*)d_in[3];
    const int*   node_i     = (const int*)d_in[4];
    const float* edge_w     = (const float*)d_in[5];
    const float* edge_p     = (const float*)d_in[6];
    const float* Wc         = (const float*)d_in[7];
    const float* bc         = (const float*)d_in[8];
    const float* Wl         = (const float*)d_in[9];
    float* out = (float*)d_out;

    const int N = in_sizes[2];
    const int E = in_sizes[3];
    const int B = in_sizes[1] / COND_DIM;

    char* ws = (char*)d_ws;
    float* gamma     = (float*)ws;  ws += (size_t)B * OUT_DIM * 4;
    float* beta      = (float*)ws;  ws += (size_t)B * OUT_DIM * 4;
    unsigned short* x   = (unsigned short*)ws;  ws += (size_t)N * OUT_DIM * 2;
    unsigned short* WlT = (unsigned short*)ws;  ws += (size_t)NODE_DIM * OUT_DIM * 2;
    int*   counts    = (int*)ws;    ws += (size_t)N * 4;
    int*   cursor    = (int*)ws;    ws += (size_t)N * 4;
    int*   row_start = (int*)ws;    ws += (size_t)(N + 4) * 4;
    int2*  epk       = (int2*)ws;   ws += (size_t)E * 8;

    int nblk = (N + TM - 1) / TM;
    prep_kernel<<<48, 256, 0, stream>>>(Wl, WlT, cond_feats, Wc, bc, gamma, beta,
                                        counts, 2 * N);
    node_mfma_kernel<<<nblk, 256, 0, stream>>>(node_feats, WlT, batch_ids, gamma, beta,
                                               x, N, node_i, counts, E);
    scan_kernel<<<1, SCAN_T, 0, stream>>>(counts, row_start, N);
    fill_kernel<<<(E + 255) / 256, 256, 0, stream>>>(node_j, node_i, edge_w, edge_p,
                                                     row_start, cursor, epk, E);
    agg_kernel<<<(N + 3) / 4, 256, 0, stream>>>(x, epk, row_start, out, N);
}

// Round 4
// 206.667 us; speedup vs baseline: 1.1804x; 1.1804x over previous
//
#include <hip/hip_runtime.h>
#include <hip/hip_bf16.h>

#define OUT_DIM 256
#define COND_DIM 512
#define NODE_DIM 256
#define TM 32            // rows per node-block
#define LDA 264          // bf16 A-tile row stride (+8 pad)
#define LN_EPS 1e-5f

typedef __attribute__((ext_vector_type(8))) short bf16x8;
typedef __attribute__((ext_vector_type(4))) float f32x4;

__device__ inline unsigned short f2bf(float f) {
    unsigned u = __float_as_uint(f);
    u += 0x7fffu + ((u >> 16) & 1u);           // RNE
    return (unsigned short)(u >> 16);
}
__device__ inline float bf2f(unsigned short b) {
    return __uint_as_float((unsigned)b << 16);
}

// ---------------- fused: degree count + Wl->bf16 transpose + FiLM params
// grid = 256 blocks: all count; [0,16) convb tiles; [16,48) film columns
__global__ __launch_bounds__(256) void prep_kernel(
        const float* __restrict__ Wl, unsigned short* __restrict__ WlT,
        const float* __restrict__ cond, const float* __restrict__ Wc,
        const float* __restrict__ bc, float* __restrict__ gamma, float* __restrict__ beta,
        const int* __restrict__ ni, int* __restrict__ counts, int E) {
    __shared__ float lds[64 * 65];
    // grid-stride degree count (counts zeroed by preceding memset)
    for (int e = blockIdx.x * 256 + threadIdx.x; e < E; e += gridDim.x * 256)
        atomicAdd(&counts[ni[e]], 1);

    if (blockIdx.x < 16) {
        float (*tile)[65] = (float(*)[65])lds;
        int bx = blockIdx.x & 3, by = blockIdx.x >> 2;
        int tr = threadIdx.x >> 6, tc = threadIdx.x & 63;
        #pragma unroll
        for (int rr = 0; rr < 64; rr += 4)
            tile[rr + tr][tc] = Wl[(by * 64 + rr + tr) * OUT_DIM + bx * 64 + tc];
        __syncthreads();
        #pragma unroll
        for (int rr = 0; rr < 64; rr += 4) {
            int n = bx * 64 + rr + tr;
            int k = by * 64 + tc;
            WlT[n * NODE_DIM + k] = f2bf(tile[tc][rr + tr]);
        }
    } else if (blockIdx.x < 48) {
        int bf = blockIdx.x - 16;
        int b = bf >> 1, half = bf & 1;
        int o = half * 256 + threadIdx.x;
        float* c = lds;
        for (int k = threadIdx.x; k < COND_DIM; k += 256) c[k] = cond[b * COND_DIM + k];
        __syncthreads();
        float acc = bc[o];
        for (int k = 0; k < COND_DIM; k += 4) {
            float4 cv = *(const float4*)&c[k];
            acc += cv.x * Wc[(k + 0) * 512 + o];
            acc += cv.y * Wc[(k + 1) * 512 + o];
            acc += cv.z * Wc[(k + 2) * 512 + o];
            acc += cv.w * Wc[(k + 3) * 512 + o];
        }
        if (half == 0) gamma[b * 256 + threadIdx.x] = acc + 1.0f;
        else           beta[b * 256 + threadIdx.x] = acc;
    }
}

// ---------------- x(bf16) = relu(LN(nf @ Wl) * gamma[bid] + beta[bid]) via MFMA
// 625 MFMA blocks (TM=32 rows, 4 waves: rows (w&1)*16, cols (w>>1)*128)
// + 1 extra block that performs the exclusive scan counts -> row_start
__global__ __launch_bounds__(256) void node_mfma_kernel(
        const float* __restrict__ nf, const unsigned short* __restrict__ WlT,
        const int* __restrict__ batch_ids, const float* __restrict__ gamma,
        const float* __restrict__ beta, unsigned short* __restrict__ xout, int N,
        const int* __restrict__ counts, int* __restrict__ row_start) {
    __shared__ unsigned short Atile[TM * LDA];     // ~17 KB
    __shared__ float part_s[TM][2], part_s2[TM][2];
    __shared__ int bid_s[TM];
    __shared__ int ssum[256];
    int t = threadIdx.x;

    if (blockIdx.x == gridDim.x - 1) {
        // ---- exclusive scan of counts[0..N) -> row_start[0..N] (counts ready: prep
        // completed before this dispatch started)
        const int P = 80;                          // 256*80 = 20480 >= N
        int base = t * P;
        int sum = 0;
        if (base < N) {
            if (base + P <= N) {
                for (int i = 0; i < P; i += 4) {
                    int4 v = *(const int4*)&counts[base + i];
                    sum += v.x + v.y + v.z + v.w;
                }
            } else {
                for (int i = 0; i < P; ++i)
                    if (base + i < N) sum += counts[base + i];
            }
        }
        ssum[t] = sum;
        __syncthreads();
        for (int off = 1; off < 256; off <<= 1) {
            int v = (t >= off) ? ssum[t - off] : 0;
            __syncthreads();
            ssum[t] += v;
            __syncthreads();
        }
        int run = ssum[t] - sum;
        if (base < N) {
            if (base + P <= N) {
                for (int i = 0; i < P; i += 4) {
                    int4 v = *(const int4*)&counts[base + i];   // L2-hot reload
                    int4 w;
                    w.x = run; w.y = run + v.x; w.z = w.y + v.y; w.w = w.z + v.z;
                    *(int4*)&row_start[base + i] = w;
                    run = w.w + v.w;
                }
            } else {
                for (int i = 0; i < P; ++i)
                    if (base + i < N) { row_start[base + i] = run; run += counts[base + i]; }
            }
        }
        if (t == 255) row_start[N] = ssum[255];
        return;
    }

    int n0 = blockIdx.x * TM;

    // stage A: 32 rows x 256 fp32 -> bf16 LDS (coalesced float4 loads)
    #pragma unroll
    for (int it = 0; it < 8; ++it) {
        int idx = t + it * 256;                    // 0..2047
        int r = idx >> 6;
        int c4 = idx & 63;
        int row = n0 + r;
        float4 v;
        if (row < N) v = *(const float4*)&nf[(size_t)row * NODE_DIM + c4 * 4];
        else         v = make_float4(0.f, 0.f, 0.f, 0.f);
        unsigned* dst = (unsigned*)&Atile[r * LDA + c4 * 4];
        dst[0] = (unsigned)f2bf(v.x) | ((unsigned)f2bf(v.y) << 16);
        dst[1] = (unsigned)f2bf(v.z) | ((unsigned)f2bf(v.w) << 16);
    }
    if (t < TM) bid_s[t] = (n0 + t < N) ? batch_ids[n0 + t] : 0;
    __syncthreads();

    int wave = t >> 6;
    int lane = t & 63;
    int l = lane & 15;
    int quad = lane >> 4;
    int rowbase = (wave & 1) * 16;                 // local row base for this wave
    int colbase = (wave >> 1) * 128;               // col base for this wave
    int half = wave >> 1;

    f32x4 acc[8];
    #pragma unroll
    for (int ct = 0; ct < 8; ++ct) acc[ct] = (f32x4){0.f, 0.f, 0.f, 0.f};

    const unsigned short* Abase = &Atile[(rowbase + l) * LDA + quad * 8];
    const unsigned short* Bbase = &WlT[(colbase + l) * NODE_DIM + quad * 8];

    #pragma unroll
    for (int ks = 0; ks < 8; ++ks) {
        bf16x8 a = *(const bf16x8*)(Abase + ks * 32);
        #pragma unroll
        for (int ct = 0; ct < 8; ++ct) {
            bf16x8 b = *(const bf16x8*)(Bbase + ct * 16 * NODE_DIM + ks * 32);
            acc[ct] = __builtin_amdgcn_mfma_f32_16x16x32_bf16(a, b, acc[ct], 0, 0, 0);
        }
    }

    // per-wave LN partials over this wave's 128 cols; rows = rowbase + quad*4 + reg
    #pragma unroll
    for (int reg = 0; reg < 4; ++reg) {
        float s = 0.f, s2 = 0.f;
        #pragma unroll
        for (int ct = 0; ct < 8; ++ct) {
            float v = acc[ct][reg];
            s += v; s2 += v * v;
        }
        #pragma unroll
        for (int off = 1; off <= 8; off <<= 1) {
            s += __shfl_xor(s, off);
            s2 += __shfl_xor(s2, off);
        }
        if (l == 0) {
            int r = rowbase + quad * 4 + reg;
            part_s[r][half] = s;
            part_s2[r][half] = s2;
        }
    }
    __syncthreads();

    // combine halves, FiLM, relu, bf16 store
    #pragma unroll
    for (int reg = 0; reg < 4; ++reg) {
        int lrow = rowbase + quad * 4 + reg;
        float S = part_s[lrow][0] + part_s[lrow][1];
        float S2 = part_s2[lrow][0] + part_s2[lrow][1];
        float mu = S * (1.f / OUT_DIM);
        float var = S2 * (1.f / OUT_DIM) - mu * mu;
        float rs = rsqrtf(var + LN_EPS);
        int grow = n0 + lrow;
        int bid = bid_s[lrow];
        const float* gg = &gamma[bid * OUT_DIM];
        const float* gb = &beta[bid * OUT_DIM];
        if (grow < N) {
            unsigned short* orow = &xout[(size_t)grow * OUT_DIM];
            #pragma unroll
            for (int ct = 0; ct < 8; ++ct) {
                int col = colbase + ct * 16 + l;
                float v = (acc[ct][reg] - mu) * rs;
                v = v * gg[col] + gb[col];
                orow[col] = f2bf(fmaxf(v, 0.f));
            }
        }
    }
}

// ---------------- CSR fill (packed src idx + weight)
__global__ void fill_kernel(const int* __restrict__ nj, const int* __restrict__ ni,
                            const float* __restrict__ ew, const float* __restrict__ ep,
                            const int* __restrict__ row_start, int* __restrict__ cursor,
                            int2* __restrict__ epk, int E) {
    int e = blockIdx.x * blockDim.x + threadIdx.x;
    if (e < E) {
        int i = ni[e];
        int pos = row_start[i] + atomicAdd(&cursor[i], 1);
        epk[pos] = make_int2(nj[e], __float_as_int(ew[e] * ep[e]));
    }
}

// ---------------- aggregation: one wave per destination node, bf16 gather
__global__ void agg_kernel(const unsigned short* __restrict__ x, const int2* __restrict__ epk,
                           const int* __restrict__ row_start, float* __restrict__ out, int N) {
    int node = blockIdx.x * 4 + (threadIdx.x >> 6);
    int lane = threadIdx.x & 63;
    if (node >= N) return;
    int s = row_start[node], e = row_start[node + 1];
    float a0 = 0.f, a1 = 0.f, a2 = 0.f, a3 = 0.f;
    for (int p = s; p < e; ++p) {
        int2 pk = epk[p];
        int j = pk.x;
        float w = __int_as_float(pk.y);
        ushort4 xv = *(const ushort4*)&x[(size_t)j * OUT_DIM + lane * 4];
        a0 += bf2f(xv.x) * w;
        a1 += bf2f(xv.y) * w;
        a2 += bf2f(xv.z) * w;
        a3 += bf2f(xv.w) * w;
    }
    float4 o;
    o.x = fmaxf(a0, 0.f); o.y = fmaxf(a1, 0.f);
    o.z = fmaxf(a2, 0.f); o.w = fmaxf(a3, 0.f);
    *(float4*)&out[(size_t)node * OUT_DIM + lane * 4] = o;
}

extern "C" void kernel_launch(void* const* d_in, const int* in_sizes, int n_in,
                              void* d_out, int out_size, void* d_ws, size_t ws_size,
                              hipStream_t stream) {
    const float* node_feats = (const float*)d_in[0];
    const float* cond_feats = (const float*)d_in[1];
    const int*   batch_ids  = (const int*)d_in[2];
    const int*   node_j     = (const int*)d_in[3];
    const int*   node_i     = (const int*)d_in[4];
    const float* edge_w     = (const float*)d_in[5];
    const float* edge_p     = (const float*)d_in[6];
    const float* Wc         = (const float*)d_in[7];
    const float* bc         = (const float*)d_in[8];
    const float* Wl         = (const float*)d_in[9];
    float* out = (float*)d_out;

    const int N = in_sizes[2];
    const int E = in_sizes[3];
    const int B = in_sizes[1] / COND_DIM;

    char* ws = (char*)d_ws;
    float* gamma     = (float*)ws;  ws += (size_t)B * OUT_DIM * 4;
    float* beta      = (float*)ws;  ws += (size_t)B * OUT_DIM * 4;
    unsigned short* x   = (unsigned short*)ws;  ws += (size_t)N * OUT_DIM * 2;
    unsigned short* WlT = (unsigned short*)ws;  ws += (size_t)NODE_DIM * OUT_DIM * 2;
    int*   counts    = (int*)ws;    ws += (size_t)N * 4;
    int*   cursor    = (int*)ws;    ws += (size_t)N * 4;
    int*   row_start = (int*)ws;    ws += (size_t)(N + 4) * 4;
    int2*  epk       = (int2*)ws;   ws += (size_t)E * 8;

    int nblk = (N + TM - 1) / TM;

    hipMemsetAsync(counts, 0, (size_t)N * 2 * 4, stream);   // counts + cursor adjacent
    prep_kernel<<<256, 256, 0, stream>>>(Wl, WlT, cond_feats, Wc, bc, gamma, beta,
                                         node_i, counts, E);
    node_mfma_kernel<<<nblk + 1, 256, 0, stream>>>(node_feats, WlT, batch_ids, gamma, beta,
                                                   x, N, counts, row_start);
    fill_kernel<<<(E + 255) / 256, 256, 0, stream>>>(node_j, node_i, edge_w, edge_p,
                                                     row_start, cursor, epk, E);
    agg_kernel<<<(N + 3) / 4, 256, 0, stream>>>(x, epk, row_start, out, N);
}